// Round 11
// baseline (995.599 us; speedup 1.0000x reference)
//
#include <hip/hip_runtime.h>
#include <hip/hip_bf16.h>

typedef short bf16x8 __attribute__((ext_vector_type(8)));
typedef float f32x16 __attribute__((ext_vector_type(16)));
typedef int   i32x4v __attribute__((ext_vector_type(4)));
typedef unsigned u32;

#define MFMA32(a,b,c) __builtin_amdgcn_mfma_f32_32x32x16_bf16((a),(b),(c),0,0,0)

__device__ __forceinline__ u32 pkbf(float x, float y) {
  union { u32 u; __hip_bfloat16 h[2]; } t;
  t.h[0] = __float2bfloat16(x);
  t.h[1] = __float2bfloat16(y);
  return t.u;
}
__device__ __forceinline__ float bf2f(u32 lo16) {
  union { u32 u; float f; } t; t.u = lo16 << 16; return t.f;
}
__device__ __forceinline__ float silu_f(float v) { return v / (1.f + __expf(-v)); }
__device__ __forceinline__ float tanh_f(float v) {
  float e = __expf(2.f * fabsf(v));
  float t = 1.f - 2.f / (e + 1.f);
  return copysignf(t, v);
}

// Stage [128][128] f32 weight block (row k = in, col j = out) into LDS
// transposed bf16 wA[j][k] with 16B-unit XOR swizzle.
template<int NT>
__device__ __forceinline__ void stage_w128t(const float* __restrict__ W, short* wA, int tid) {
  for (int p = tid; p < 8192; p += NT) {
    int j = p & 127;
    int k = (p >> 7) << 1;
    u32 u = pkbf(W[k * 128 + j], W[k * 128 + 128 + j]);
    int off = j * 256 + (((k >> 3) ^ (j & 15)) << 4) + ((k & 7) << 1);
    *(u32*)((char*)wA + off) = u;
  }
}
__device__ __forceinline__ bf16x8 ldsA(const short* wA, int j, int kbase) {
  int off = j * 256 + (((kbase >> 3) ^ (j & 15)) << 4);
  return __builtin_bit_cast(bf16x8, *(const i32x4v*)((const char*)wA + off));
}

// Store one jm-block (32 dims) of a row as 2x16B chunks per lane,
// after a hi-pair exchange. Layout matches the kc*32+hi*16 B-fragment loads.
__device__ __forceinline__ void row_chunks(u32 p0, u32 p1, u32 p2, u32 p3,
                                           u32 p4, u32 p5, u32 p6, u32 p7,
                                           int hi, char* rowptr, int jm) {
  u32 x0 = (u32)__shfl_xor((int)(hi ? p0 : p4), 32);
  u32 x1 = (u32)__shfl_xor((int)(hi ? p1 : p5), 32);
  u32 x2 = (u32)__shfl_xor((int)(hi ? p2 : p6), 32);
  u32 x3 = (u32)__shfl_xor((int)(hi ? p3 : p7), 32);
  i32x4v c0, c1;
  if (hi) {
    c0[0] = (int)x0; c0[1] = (int)x1; c0[2] = (int)p4; c0[3] = (int)p5;
    c1[0] = (int)x2; c1[1] = (int)x3; c1[2] = (int)p6; c1[3] = (int)p7;
  } else {
    c0[0] = (int)p0; c0[1] = (int)p1; c0[2] = (int)x0; c0[3] = (int)x1;
    c1[0] = (int)p2; c1[1] = (int)p3; c1[2] = (int)x2; c1[3] = (int)x3;
  }
  *(i32x4v*)(rowptr + jm * 64 + hi * 32)      = c0;
  *(i32x4v*)(rowptr + jm * 64 + hi * 32 + 16) = c1;
}

// One jm (global index) of C-layout -> silu(+bias) -> row store.
__device__ __forceinline__ void trans_store1(const f32x16& a, const float* bias, int hi,
                                             char* rowptr, bool va, int jm) {
  float v[16];
  #pragma unroll
  for (int r = 0; r < 16; ++r) {
    int rowloc = (r & 3) + 8 * (r >> 2) + 4 * hi;
    v[r] = silu_f(a[r] + bias[jm * 32 + rowloc]);
  }
  u32 p0 = pkbf(v[0], v[1]),  p1 = pkbf(v[2], v[3]);
  u32 p2 = pkbf(v[4], v[5]),  p3 = pkbf(v[6], v[7]);
  u32 p4 = pkbf(v[8], v[9]),  p5 = pkbf(v[10], v[11]);
  u32 p6 = pkbf(v[12], v[13]), p7 = pkbf(v[14], v[15]);
  if (va) row_chunks(p0, p1, p2, p3, p4, p5, p6, p7, hi, rowptr, jm);
}

// One jm: C-layout -> silu(+bias) -> B-frags (fr[jm*2], fr[jm*2+1]) + optional row store.
__device__ __forceinline__ void trans_frag1(const f32x16& a, const float* bias, int hi,
                                            i32x4v* fr, char* rowptr, bool va, int jm) {
  float v[16];
  #pragma unroll
  for (int r = 0; r < 16; ++r) {
    int rowloc = (r & 3) + 8 * (r >> 2) + 4 * hi;
    v[r] = silu_f(a[r] + bias[jm * 32 + rowloc]);
  }
  u32 p0 = pkbf(v[0], v[1]),  p1 = pkbf(v[2], v[3]);
  u32 p2 = pkbf(v[4], v[5]),  p3 = pkbf(v[6], v[7]);
  u32 p4 = pkbf(v[8], v[9]),  p5 = pkbf(v[10], v[11]);
  u32 p6 = pkbf(v[12], v[13]), p7 = pkbf(v[14], v[15]);
  {
    u32 g1 = (u32)__shfl_xor((int)(hi ? p0 : p2), 32);
    u32 g2 = (u32)__shfl_xor((int)(hi ? p1 : p3), 32);
    i32x4v w;
    w[0] = hi ? (int)g1 : (int)p0;
    w[1] = hi ? (int)g2 : (int)p1;
    w[2] = hi ? (int)p2 : (int)g1;
    w[3] = hi ? (int)p3 : (int)g2;
    fr[jm * 2] = w;
    u32 g1b = (u32)__shfl_xor((int)(hi ? p4 : p6), 32);
    u32 g2b = (u32)__shfl_xor((int)(hi ? p5 : p7), 32);
    i32x4v w2;
    w2[0] = hi ? (int)g1b : (int)p4;
    w2[1] = hi ? (int)g2b : (int)p5;
    w2[2] = hi ? (int)p6 : (int)g1b;
    w2[3] = hi ? (int)p7 : (int)g2b;
    fr[jm * 2 + 1] = w2;
  }
  if (va) row_chunks(p0, p1, p2, p3, p4, p5, p6, p7, hi, rowptr, jm);
}

// ===================== PIPELINE =====================

__global__ void kconv(const float* __restrict__ h, char* __restrict__ hbf, int total16) {
  int i = blockIdx.x * 256 + threadIdx.x;
  if (i >= total16) return;
  const float4* h4 = (const float4*)h;
  float4 a = h4[(size_t)i * 2], b = h4[(size_t)i * 2 + 1];
  i32x4v w;
  w[0] = (int)pkbf(a.x, a.y); w[1] = (int)pkbf(a.z, a.w);
  w[2] = (int)pkbf(b.x, b.y); w[3] = (int)pkbf(b.z, b.w);
  *(i32x4v*)(hbf + (size_t)i * 16) = w;
}

__global__ void khist(const int* __restrict__ src, int* __restrict__ cnt, int E) {
  int e = blockIdx.x * 256 + threadIdx.x;
  if (e < E) atomicAdd(&cnt[src[e]], 1);
}

__global__ void kscan1(const int* __restrict__ cnt, int* __restrict__ part,
                       int* __restrict__ bsums, int N) {
  __shared__ int sh[1024];
  int tid = threadIdx.x, i = blockIdx.x * 1024 + tid;
  int v = (i < N) ? cnt[i] : 0;
  sh[tid] = v; __syncthreads();
  for (int off = 1; off < 1024; off <<= 1) {
    int t = (tid >= off) ? sh[tid - off] : 0;
    __syncthreads();
    sh[tid] += t;
    __syncthreads();
  }
  if (i < N) part[i] = sh[tid] - v;
  if (tid == 1023) bsums[blockIdx.x] = sh[1023];
}

__global__ void kscan2(int* __restrict__ bsums, int nb) {
  __shared__ int sh[64];
  int tid = threadIdx.x;
  int v = (tid < nb) ? bsums[tid] : 0;
  sh[tid] = v; __syncthreads();
  for (int off = 1; off < 64; off <<= 1) {
    int t = (tid >= off) ? sh[tid - off] : 0;
    __syncthreads();
    sh[tid] += t;
    __syncthreads();
  }
  if (tid < nb) bsums[tid] = sh[tid] - v;
}

__global__ void kscan3(const int* __restrict__ bsums, int* __restrict__ part,
                       int* __restrict__ head, int N) {
  int i = blockIdx.x * 1024 + threadIdx.x;
  if (i < N) {
    int v = part[i] + bsums[blockIdx.x];
    part[i] = v;
    head[i] = v;
  }
}

// Scatter packed 32B edge records to sorted slots.
__global__ void kscatter(const int* __restrict__ src, const int* __restrict__ dst,
                         const float* __restrict__ dist, const float* __restrict__ bpp,
                         const float* __restrict__ msa, const float* __restrict__ chem,
                         const float* __restrict__ rel, const float* __restrict__ cbm,
                         int* __restrict__ head, int* __restrict__ rec, int E) {
  int e = blockIdx.x * 256 + threadIdx.x;
  if (e >= E) return;
  int s = src[e];
  int p = atomicAdd(&head[s], 1);
  float q = dist[e];
  i32x4v a;
  a[0] = s;
  a[1] = dst[e];
  a[2] = (int)pkbf(q * q, bpp[e]);
  a[3] = (int)pkbf(msa[e], chem[e]);
  *(i32x4v*)(rec + (size_t)p * 8) = a;
  rec[(size_t)p * 8 + 4] = (int)pkbf(rel[e], cbm[e]);
}

// FUSED edge pipeline: layer1 -> layer2 (m store) -> c-layer (coef), one
// pass over edges, no t1 round-trip. Single b[8] buffer: src rows ->
// (overwritten) dst rows during GEMM1a -> next tile's src rows after GEMM2.
// Register peak ~112: layer1 b(32)+acc(64); later fr1/fr2/acc2 phases <=96.
__global__ __launch_bounds__(512, 2)
void kedgeAB(const char* __restrict__ hbf, const int* __restrict__ rec,
             const float* __restrict__ mW1, const float* __restrict__ mb1,
             const float* __restrict__ mW2, const float* __restrict__ mb2,
             const float* __restrict__ cW1, const float* __restrict__ cb1,
             const float* __restrict__ cW2v, const float* __restrict__ cb2,
             char* __restrict__ m_ij, float* __restrict__ coef, int E)
{
  __shared__ short wA0[16384], wA1[16384], wA2[16384], wA3[16384];  // 128 KB
  __shared__ short wE[2048];                                        // 4 KB
  __shared__ float sb1[128], sb2[128], scb1[128], scw2[128];
  __shared__ float scb2v[1];

  const int tid = threadIdx.x, wid = tid >> 6, lane = tid & 63;
  const int col = lane & 31, hi = lane >> 5;

  stage_w128t<512>(mW1, wA0, tid);
  stage_w128t<512>(mW1 + 16384, wA1, tid);
  stage_w128t<512>(mW2, wA2, tid);
  stage_w128t<512>(cW1, wA3, tid);
  for (int p = tid; p < 2048; p += 512) {
    int j = p >> 4, kk = p & 15;
    float w = (kk < 6) ? mW1[(256 + kk) * 128 + j] : 0.f;
    wE[j * 16 + kk] = (short)(pkbf(w, 0.f) & 0xffffu);
  }
  if (tid < 128) {
    sb1[tid] = mb1[tid]; sb2[tid] = mb2[tid];
    scb1[tid] = cb1[tid]; scw2[tid] = cW2v[tid];
  }
  if (tid == 0) scb2v[0] = cb2[0];
  __syncthreads();

  const int T = (E + 31) / 32;
  const int stride = gridDim.x * 8;
  int t = blockIdx.x * 8 + wid;
  if (t >= T) return;

  int p = t * 32 + col;
  int pc = p < E ? p : E - 1;
  i32x4v ra = *(const i32x4v*)(rec + (size_t)pc * 8);
  int ev2 = rec[(size_t)pc * 8 + 4];

  // preload first tile's src rows
  i32x4v b[8];
  #pragma unroll
  for (int kc = 0; kc < 8; ++kc)
    b[kc] = *(const i32x4v*)(hbf + (size_t)ra[0] * 256 + kc * 32 + hi * 16);

  while (t < T) {
    bool va = p < E;

    int tn = t + stride;
    int pn = tn * 32 + col;
    int pcn = pn < E ? pn : E - 1;
    i32x4v nra = *(const i32x4v*)(rec + (size_t)pcn * 8);
    int nev2 = rec[(size_t)pcn * 8 + 4];

    // ---- layer1: acc[4], b = src rows, overwritten by dst rows in GEMM1a
    f32x16 acc[4];
    #pragma unroll
    for (int jm = 0; jm < 4; ++jm)
      #pragma unroll
      for (int r = 0; r < 16; ++r) acc[jm][r] = 0.f;

    #pragma unroll
    for (int kc = 0; kc < 8; ++kc) {
      bf16x8 bb = __builtin_bit_cast(bf16x8, b[kc]);
      b[kc] = *(const i32x4v*)(hbf + (size_t)ra[1] * 256 + kc * 32 + hi * 16);
      #pragma unroll
      for (int jm = 0; jm < 4; ++jm)
        acc[jm] = MFMA32(ldsA(wA0, jm * 32 + col, kc * 16 + hi * 8), bb, acc[jm]);
    }
    #pragma unroll
    for (int kc = 0; kc < 8; ++kc) {
      bf16x8 bb = __builtin_bit_cast(bf16x8, b[kc]);
      #pragma unroll
      for (int jm = 0; jm < 4; ++jm)
        acc[jm] = MFMA32(ldsA(wA1, jm * 32 + col, kc * 16 + hi * 8), bb, acc[jm]);
    }
    {
      i32x4v ev;
      ev[0] = hi ? 0 : ra[2];
      ev[1] = hi ? 0 : ra[3];
      ev[2] = hi ? 0 : ev2;
      ev[3] = 0;
      bf16x8 be = __builtin_bit_cast(bf16x8, ev);
      #pragma unroll
      for (int jm = 0; jm < 4; ++jm) {
        bf16x8 af = __builtin_bit_cast(bf16x8,
            *(const i32x4v*)((const char*)wE + (jm * 32 + col) * 32 + hi * 16));
        acc[jm] = MFMA32(af, be, acc[jm]);
      }
    }

    // t1 -> fr1 (register B-frags, no memory)
    i32x4v fr1[8];
    #pragma unroll
    for (int jm = 0; jm < 4; ++jm)
      trans_frag1(acc[jm], sb1, hi, fr1, nullptr, false, jm);

    // ---- layer2: acc2 two-pass, m -> fr2 + slot store
    char* rowptr = m_ij + (size_t)p * 256;
    i32x4v fr2[8];
    #pragma unroll
    for (int g = 0; g < 2; ++g) {
      f32x16 acc2[2];
      #pragma unroll
      for (int j2 = 0; j2 < 2; ++j2)
        #pragma unroll
        for (int r = 0; r < 16; ++r) acc2[j2][r] = 0.f;
      #pragma unroll
      for (int kc = 0; kc < 8; ++kc) {
        bf16x8 bb = __builtin_bit_cast(bf16x8, fr1[kc]);
        #pragma unroll
        for (int j2 = 0; j2 < 2; ++j2)
          acc2[j2] = MFMA32(ldsA(wA2, (g * 2 + j2) * 32 + col, kc * 16 + hi * 8), bb, acc2[j2]);
      }
      #pragma unroll
      for (int j2 = 0; j2 < 2; ++j2)
        trans_frag1(acc2[j2], sb2, hi, fr2, rowptr, va, g * 2 + j2);
    }

    // fr1 dead -> prefetch next tile's src rows into b (covered by GEMM3)
    #pragma unroll
    for (int kc = 0; kc < 8; ++kc)
      b[kc] = *(const i32x4v*)(hbf + (size_t)nra[0] * 256 + kc * 32 + hi * 16);

    // ---- c-layer: acc2 two-pass on fr2, reduce to coef
    float part = 0.f;
    #pragma unroll
    for (int g = 0; g < 2; ++g) {
      f32x16 acc2[2];
      #pragma unroll
      for (int j2 = 0; j2 < 2; ++j2)
        #pragma unroll
        for (int r = 0; r < 16; ++r) acc2[j2][r] = 0.f;
      #pragma unroll
      for (int kc = 0; kc < 8; ++kc) {
        bf16x8 bb = __builtin_bit_cast(bf16x8, fr2[kc]);
        #pragma unroll
        for (int j2 = 0; j2 < 2; ++j2)
          acc2[j2] = MFMA32(ldsA(wA3, (g * 2 + j2) * 32 + col, kc * 16 + hi * 8), bb, acc2[j2]);
      }
      #pragma unroll
      for (int j2 = 0; j2 < 2; ++j2) {
        int jm = g * 2 + j2;
        #pragma unroll
        for (int r = 0; r < 16; ++r) {
          int rowloc = (r & 3) + 8 * (r >> 2) + 4 * hi;
          part += silu_f(acc2[j2][r] + scb1[jm * 32 + rowloc]) * scw2[jm * 32 + rowloc];
        }
      }
    }
    part += __shfl_xor(part, 32);
    float cf = tanh_f(part + scb2v[0]);
    if (va && hi == 0) coef[p] = cf;

    t = tn; p = pn; ra = nra; ev2 = nev2;
  }
}

// Streaming segmented sum over sorted slots: 16 threads per node.
__global__ __launch_bounds__(256)
void kagg(const char* __restrict__ m_ij, const int* __restrict__ row_start,
          const int* __restrict__ cnt, const float* __restrict__ coef,
          const int* __restrict__ rec, const float* __restrict__ x,
          char* __restrict__ mibf, float* __restrict__ outX, int N)
{
  int n = blockIdx.x * 16 + (threadIdx.x >> 4);
  int t = threadIdx.x & 15;
  if (n >= N) return;
  int st = row_start[n], c = cnt[n];
  float a[8] = {0.f, 0.f, 0.f, 0.f, 0.f, 0.f, 0.f, 0.f};
  for (int k = 0; k < c; ++k) {
    i32x4v u = *(const i32x4v*)(m_ij + (size_t)(st + k) * 256 + t * 16);
    #pragma unroll
    for (int q = 0; q < 4; ++q) {
      u32 w = (u32)u[q];
      a[q * 2]     += bf2f(w & 0xffffu);
      a[q * 2 + 1] += bf2f(w >> 16);
    }
  }
  float inv = 1.f / fmaxf((float)c, 1.f);
  i32x4v o;
  #pragma unroll
  for (int q = 0; q < 4; ++q) o[q] = (int)pkbf(a[q * 2] * inv, a[q * 2 + 1] * inv);
  *(i32x4v*)(mibf + (size_t)n * 256 + t * 16) = o;
  if (t == 0) {
    float x0 = x[(size_t)n * 3], x1 = x[(size_t)n * 3 + 1], x2 = x[(size_t)n * 3 + 2];
    float dx = 0.f, dy = 0.f, dz = 0.f;
    for (int k = 0; k < c; ++k) {
      float cf = coef[st + k];
      int dn = rec[(size_t)(st + k) * 8 + 1];
      dx += (x0 - x[(size_t)dn * 3])     * cf;
      dy += (x1 - x[(size_t)dn * 3 + 1]) * cf;
      dz += (x2 - x[(size_t)dn * 3 + 2]) * cf;
    }
    outX[(size_t)n * 3]     = x0 + dx * inv;
    outX[(size_t)n * 3 + 1] = x1 + dy * inv;
    outX[(size_t)n * 3 + 2] = x2 + dz * inv;
  }
}

// Node MLP layer1: t1h = silu([h | m_i] . hW1 + b1)
__global__ __launch_bounds__(512, 2)
void knode1(const char* __restrict__ hbf, const char* __restrict__ mibf,
            const float* __restrict__ hW1, const float* __restrict__ hb1,
            char* __restrict__ t1h, int N)
{
  __shared__ short wA0[16384], wA1[16384];
  __shared__ float sb1[128];
  const int tid = threadIdx.x, wid = tid >> 6, lane = tid & 63;
  const int col = lane & 31, hi = lane >> 5;
  stage_w128t<512>(hW1, wA0, tid);
  stage_w128t<512>(hW1 + 16384, wA1, tid);
  if (tid < 128) sb1[tid] = hb1[tid];
  __syncthreads();

  int T = (N + 31) / 32;
  int t = blockIdx.x * 8 + wid;
  if (t >= T) return;
  int n = t * 32 + col;
  bool va = n < N;
  int nc = va ? n : N - 1;

  i32x4v bh[8], bm[8];
  #pragma unroll
  for (int kc = 0; kc < 8; ++kc)
    bh[kc] = *(const i32x4v*)(hbf + (size_t)nc * 256 + kc * 32 + hi * 16);
  #pragma unroll
  for (int kc = 0; kc < 8; ++kc)
    bm[kc] = *(const i32x4v*)(mibf + (size_t)nc * 256 + kc * 32 + hi * 16);

  char* rowptr = t1h + (size_t)n * 256;
  #pragma unroll
  for (int g = 0; g < 2; ++g) {
    f32x16 acc2[2];
    #pragma unroll
    for (int j2 = 0; j2 < 2; ++j2)
      #pragma unroll
      for (int r = 0; r < 16; ++r) acc2[j2][r] = 0.f;
    #pragma unroll
    for (int kc = 0; kc < 8; ++kc) {
      bf16x8 bb = __builtin_bit_cast(bf16x8, bh[kc]);
      #pragma unroll
      for (int j2 = 0; j2 < 2; ++j2)
        acc2[j2] = MFMA32(ldsA(wA0, (g * 2 + j2) * 32 + col, kc * 16 + hi * 8), bb, acc2[j2]);
    }
    #pragma unroll
    for (int kc = 0; kc < 8; ++kc) {
      bf16x8 bb = __builtin_bit_cast(bf16x8, bm[kc]);
      #pragma unroll
      for (int j2 = 0; j2 < 2; ++j2)
        acc2[j2] = MFMA32(ldsA(wA1, (g * 2 + j2) * 32 + col, kc * 16 + hi * 8), bb, acc2[j2]);
    }
    #pragma unroll
    for (int j2 = 0; j2 < 2; ++j2)
      trans_store1(acc2[j2], sb1, hi, rowptr, va, g * 2 + j2);
  }
}

// Node MLP layer2 + residual: h_out = h + t1h . hW2 + b2
__global__ __launch_bounds__(512, 2)
void knode2(const char* __restrict__ t1h, const float* __restrict__ hW2,
            const float* __restrict__ hb2, const float* __restrict__ h,
            float* __restrict__ outH, int N)
{
  __shared__ short wA0[16384];
  __shared__ float sb2[128];
  const int tid = threadIdx.x, wid = tid >> 6, lane = tid & 63;
  const int col = lane & 31, hi = lane >> 5;
  stage_w128t<512>(hW2, wA0, tid);
  if (tid < 128) sb2[tid] = hb2[tid];
  __syncthreads();

  int T = (N + 31) / 32;
  int t = blockIdx.x * 8 + wid;
  if (t >= T) return;
  int n = t * 32 + col;
  bool va = n < N;
  int nc = va ? n : N - 1;

  i32x4v b[8];
  #pragma unroll
  for (int kc = 0; kc < 8; ++kc)
    b[kc] = *(const i32x4v*)(t1h + (size_t)nc * 256 + kc * 32 + hi * 16);

  const float4* h4 = (const float4*)h;
  #pragma unroll
  for (int g = 0; g < 2; ++g) {
    f32x16 acc2[2];
    #pragma unroll
    for (int j2 = 0; j2 < 2; ++j2)
      #pragma unroll
      for (int r = 0; r < 16; ++r) acc2[j2][r] = 0.f;
    #pragma unroll
    for (int kc = 0; kc < 8; ++kc) {
      bf16x8 bb = __builtin_bit_cast(bf16x8, b[kc]);
      #pragma unroll
      for (int j2 = 0; j2 < 2; ++j2)
        acc2[j2] = MFMA32(ldsA(wA0, (g * 2 + j2) * 32 + col, kc * 16 + hi * 8), bb, acc2[j2]);
    }
    #pragma unroll
    for (int j2 = 0; j2 < 2; ++j2) {
      int jm = g * 2 + j2;
      #pragma unroll
      for (int rq = 0; rq < 4; ++rq) {
        int j0 = jm * 32 + rq * 8 + hi * 4;
        float4 hv = h4[(size_t)nc * 32 + (j0 >> 2)];
        float4 o;
        o.x = hv.x + acc2[j2][rq * 4 + 0] + sb2[j0 + 0];
        o.y = hv.y + acc2[j2][rq * 4 + 1] + sb2[j0 + 1];
        o.z = hv.z + acc2[j2][rq * 4 + 2] + sb2[j0 + 2];
        o.w = hv.w + acc2[j2][rq * 4 + 3] + sb2[j0 + 3];
        if (va) ((float4*)outH)[(size_t)nc * 32 + (j0 >> 2)] = o;
      }
    }
  }
}

// ===================== LAUNCH =====================

extern "C" void kernel_launch(void* const* d_in, const int* in_sizes, int n_in,
                              void* d_out, int out_size, void* d_ws, size_t ws_size,
                              hipStream_t stream) {
  const float* h    = (const float*)d_in[0];
  const float* x    = (const float*)d_in[1];
  const int*   src  = (const int*)d_in[2];
  const int*   dst  = (const int*)d_in[3];
  const float* dist = (const float*)d_in[4];
  const float* bpp  = (const float*)d_in[5];
  const float* msa  = (const float*)d_in[6];
  const float* chem = (const float*)d_in[7];
  const float* rel  = (const float*)d_in[8];
  const float* cbm  = (const float*)d_in[9];
  const float* mW1  = (const float*)d_in[10];
  const float* mb1  = (const float*)d_in[11];
  const float* mW2  = (const float*)d_in[12];
  const float* mb2  = (const float*)d_in[13];
  const float* hW1  = (const float*)d_in[14];
  const float* hb1  = (const float*)d_in[15];
  const float* hW2  = (const float*)d_in[16];
  const float* hb2  = (const float*)d_in[17];
  const float* cW1  = (const float*)d_in[18];
  const float* cb1  = (const float*)d_in[19];
  const float* cW2  = (const float*)d_in[20];
  const float* cb2  = (const float*)d_in[21];

  int N = in_sizes[0] / 128;
  int E = in_sizes[2];

  size_t off = 0;
  auto A = [&](size_t b) { size_t o = off; off += (b + 255) & ~(size_t)255; return o; };
  size_t o_cnt  = A((size_t)N * 4);
  size_t o_rs   = A((size_t)N * 4);
  size_t o_head = A((size_t)N * 4);
  size_t o_rec  = A((size_t)E * 32);
  size_t o_coef = A((size_t)E * 4);
  size_t o_bs   = A(1024);
  size_t o_hbf  = A((size_t)N * 256);
  size_t o_mibf = A((size_t)N * 256);
  size_t o_big  = A((size_t)E * 256);   // m_ij -> t1h (reused)

  char* W = (char*)d_ws;
  int*   cnt32 = (int*)(W + o_cnt);
  int*   rs    = (int*)(W + o_rs);
  int*   head  = (int*)(W + o_head);
  int*   rec   = (int*)(W + o_rec);
  float* coef  = (float*)(W + o_coef);
  int*   bsums = (int*)(W + o_bs);
  char*  hbf   = W + o_hbf;
  char*  mibf  = W + o_mibf;
  char*  big   = W + o_big;

  hipMemsetAsync(cnt32, 0, (size_t)N * 4, stream);
  kconv<<<(N * 16 + 255) / 256, 256, 0, stream>>>(h, hbf, N * 16);
  khist<<<(E + 255) / 256, 256, 0, stream>>>(src, cnt32, E);
  int nb = (N + 1023) / 1024;
  kscan1<<<nb, 1024, 0, stream>>>(cnt32, rs, bsums, N);
  kscan2<<<1, 64, 0, stream>>>(bsums, nb);
  kscan3<<<nb, 1024, 0, stream>>>(bsums, rs, head, N);
  kscatter<<<(E + 255) / 256, 256, 0, stream>>>(src, dst, dist, bpp, msa, chem, rel, cbm,
                                                head, rec, E);
  kedgeAB<<<256, 512, 0, stream>>>(hbf, rec, mW1, mb1, mW2, mb2, cW1, cb1, cW2, cb2,
                                   big, coef, E);
  kagg<<<(N + 15) / 16, 256, 0, stream>>>(big, rs, cnt32, coef, rec, x,
                                          mibf, (float*)d_out + (size_t)N * 128, N);
  int tb = ((N + 31) / 32 + 7) / 8;
  knode1<<<tb, 512, 0, stream>>>(hbf, mibf, hW1, hb1, big, N);
  knode2<<<tb, 512, 0, stream>>>(big, hW2, hb2, h, (float*)d_out, N);
}

// Round 13
// 747.952 us; speedup vs baseline: 1.3311x; 1.3311x over previous
//
#include <hip/hip_runtime.h>
#include <hip/hip_bf16.h>

typedef short bf16x8 __attribute__((ext_vector_type(8)));
typedef float f32x16 __attribute__((ext_vector_type(16)));
typedef int   i32x4v __attribute__((ext_vector_type(4)));
typedef unsigned u32;

#define MFMA32(a,b,c) __builtin_amdgcn_mfma_f32_32x32x16_bf16((a),(b),(c),0,0,0)

__device__ __forceinline__ u32 pkbf(float x, float y) {
  union { u32 u; __hip_bfloat16 h[2]; } t;
  t.h[0] = __float2bfloat16(x);
  t.h[1] = __float2bfloat16(y);
  return t.u;
}
__device__ __forceinline__ float bf2f(u32 lo16) {
  union { u32 u; float f; } t; t.u = lo16 << 16; return t.f;
}
__device__ __forceinline__ float silu_f(float v) { return v / (1.f + __expf(-v)); }
__device__ __forceinline__ float tanh_f(float v) {
  float e = __expf(2.f * fabsf(v));
  float t = 1.f - 2.f / (e + 1.f);
  return copysignf(t, v);
}

template<int NT>
__device__ __forceinline__ void stage_w128t(const float* __restrict__ W, short* wA, int tid) {
  for (int p = tid; p < 8192; p += NT) {
    int j = p & 127;
    int k = (p >> 7) << 1;
    u32 u = pkbf(W[k * 128 + j], W[k * 128 + 128 + j]);
    int off = j * 256 + (((k >> 3) ^ (j & 15)) << 4) + ((k & 7) << 1);
    *(u32*)((char*)wA + off) = u;
  }
}
__device__ __forceinline__ bf16x8 ldsA(const short* wA, int j, int kbase) {
  int off = j * 256 + (((kbase >> 3) ^ (j & 15)) << 4);
  return __builtin_bit_cast(bf16x8, *(const i32x4v*)((const char*)wA + off));
}

// Store one jm-block of a row as 2x16B chunks per lane (hi-pair exchange).
__device__ __forceinline__ void row_chunks(u32 p0, u32 p1, u32 p2, u32 p3,
                                           u32 p4, u32 p5, u32 p6, u32 p7,
                                           int hi, char* rowptr, int jm) {
  u32 x0 = (u32)__shfl_xor((int)(hi ? p0 : p4), 32);
  u32 x1 = (u32)__shfl_xor((int)(hi ? p1 : p5), 32);
  u32 x2 = (u32)__shfl_xor((int)(hi ? p2 : p6), 32);
  u32 x3 = (u32)__shfl_xor((int)(hi ? p3 : p7), 32);
  i32x4v c0, c1;
  if (hi) {
    c0[0] = (int)x0; c0[1] = (int)x1; c0[2] = (int)p4; c0[3] = (int)p5;
    c1[0] = (int)x2; c1[1] = (int)x3; c1[2] = (int)p6; c1[3] = (int)p7;
  } else {
    c0[0] = (int)p0; c0[1] = (int)p1; c0[2] = (int)x0; c0[3] = (int)x1;
    c1[0] = (int)p2; c1[1] = (int)p3; c1[2] = (int)x2; c1[3] = (int)x3;
  }
  *(i32x4v*)(rowptr + jm * 64 + hi * 32)      = c0;
  *(i32x4v*)(rowptr + jm * 64 + hi * 32 + 16) = c1;
}

__device__ __forceinline__ void trans_store1(const f32x16& a, const float* bias, int hi,
                                             char* rowptr, bool va, int jm) {
  float v[16];
  #pragma unroll
  for (int r = 0; r < 16; ++r) {
    int rowloc = (r & 3) + 8 * (r >> 2) + 4 * hi;
    v[r] = silu_f(a[r] + bias[jm * 32 + rowloc]);
  }
  u32 p0 = pkbf(v[0], v[1]),  p1 = pkbf(v[2], v[3]);
  u32 p2 = pkbf(v[4], v[5]),  p3 = pkbf(v[6], v[7]);
  u32 p4 = pkbf(v[8], v[9]),  p5 = pkbf(v[10], v[11]);
  u32 p6 = pkbf(v[12], v[13]), p7 = pkbf(v[14], v[15]);
  if (va) row_chunks(p0, p1, p2, p3, p4, p5, p6, p7, hi, rowptr, jm);
}

// Build B-frags fr[jm*2], fr[jm*2+1] from post-activation values v[16].
__device__ __forceinline__ void frags_from_v(const float* v, int hi, i32x4v* fr, int jm) {
  u32 p0 = pkbf(v[0], v[1]),  p1 = pkbf(v[2], v[3]);
  u32 p2 = pkbf(v[4], v[5]),  p3 = pkbf(v[6], v[7]);
  u32 p4 = pkbf(v[8], v[9]),  p5 = pkbf(v[10], v[11]);
  u32 p6 = pkbf(v[12], v[13]), p7 = pkbf(v[14], v[15]);
  u32 g1 = (u32)__shfl_xor((int)(hi ? p0 : p2), 32);
  u32 g2 = (u32)__shfl_xor((int)(hi ? p1 : p3), 32);
  i32x4v w;
  w[0] = hi ? (int)g1 : (int)p0;
  w[1] = hi ? (int)g2 : (int)p1;
  w[2] = hi ? (int)p2 : (int)g1;
  w[3] = hi ? (int)p3 : (int)g2;
  fr[jm * 2] = w;
  u32 g1b = (u32)__shfl_xor((int)(hi ? p4 : p6), 32);
  u32 g2b = (u32)__shfl_xor((int)(hi ? p5 : p7), 32);
  i32x4v w2;
  w2[0] = hi ? (int)g1b : (int)p4;
  w2[1] = hi ? (int)g2b : (int)p5;
  w2[2] = hi ? (int)p6 : (int)g1b;
  w2[3] = hi ? (int)p7 : (int)g2b;
  fr[jm * 2 + 1] = w2;
}

// ===================== PIPELINE =====================

__global__ void kconv(const float* __restrict__ h, char* __restrict__ hbf, int total16) {
  int i = blockIdx.x * 256 + threadIdx.x;
  if (i >= total16) return;
  const float4* h4 = (const float4*)h;
  float4 a = h4[(size_t)i * 2], b = h4[(size_t)i * 2 + 1];
  i32x4v w;
  w[0] = (int)pkbf(a.x, a.y); w[1] = (int)pkbf(a.z, a.w);
  w[2] = (int)pkbf(b.x, b.y); w[3] = (int)pkbf(b.z, b.w);
  *(i32x4v*)(hbf + (size_t)i * 16) = w;
}

__global__ void khist(const int* __restrict__ src, int* __restrict__ cnt, int E) {
  int e = blockIdx.x * 256 + threadIdx.x;
  if (e < E) atomicAdd(&cnt[src[e]], 1);
}

__global__ void kscan1(const int* __restrict__ cnt, int* __restrict__ part,
                       int* __restrict__ bsums, int N) {
  __shared__ int sh[1024];
  int tid = threadIdx.x, i = blockIdx.x * 1024 + tid;
  int v = (i < N) ? cnt[i] : 0;
  sh[tid] = v; __syncthreads();
  for (int off = 1; off < 1024; off <<= 1) {
    int t = (tid >= off) ? sh[tid - off] : 0;
    __syncthreads();
    sh[tid] += t;
    __syncthreads();
  }
  if (i < N) part[i] = sh[tid] - v;
  if (tid == 1023) bsums[blockIdx.x] = sh[1023];
}

__global__ void kscan2(int* __restrict__ bsums, int nb) {
  __shared__ int sh[64];
  int tid = threadIdx.x;
  int v = (tid < nb) ? bsums[tid] : 0;
  sh[tid] = v; __syncthreads();
  for (int off = 1; off < 64; off <<= 1) {
    int t = (tid >= off) ? sh[tid - off] : 0;
    __syncthreads();
    sh[tid] += t;
    __syncthreads();
  }
  if (tid < nb) bsums[tid] = sh[tid] - v;
}

__global__ void kscan3(const int* __restrict__ bsums, int* __restrict__ part,
                       int* __restrict__ head, int N) {
  int i = blockIdx.x * 1024 + threadIdx.x;
  if (i < N) {
    int v = part[i] + bsums[blockIdx.x];
    part[i] = v;
    head[i] = v;
  }
}

__global__ void kscatter(const int* __restrict__ src, const int* __restrict__ dst,
                         const float* __restrict__ dist, const float* __restrict__ bpp,
                         const float* __restrict__ msa, const float* __restrict__ chem,
                         const float* __restrict__ rel, const float* __restrict__ cbm,
                         int* __restrict__ head, int* __restrict__ rec, int E) {
  int e = blockIdx.x * 256 + threadIdx.x;
  if (e >= E) return;
  int s = src[e];
  int p = atomicAdd(&head[s], 1);
  float q = dist[e];
  i32x4v a;
  a[0] = s;
  a[1] = dst[e];
  a[2] = (int)pkbf(q * q, bpp[e]);
  a[3] = (int)pkbf(msa[e], chem[e]);
  *(i32x4v*)(rec + (size_t)p * 8) = a;
  rec[(size_t)p * 8 + 4] = (int)pkbf(rel[e], cbm[e]);
}

// Edge layer1: t1 = silu(feat . W1 + b1). (r8-proven body)
__global__ __launch_bounds__(512, 2)
void kedgeA(const char* __restrict__ hbf, const int* __restrict__ rec,
            const float* __restrict__ mW1, const float* __restrict__ mb1,
            char* __restrict__ t1, int E)
{
  __shared__ short wA0[16384], wA1[16384];
  __shared__ short wE[2048];
  __shared__ float sb1[128];

  const int tid = threadIdx.x, wid = tid >> 6, lane = tid & 63;
  const int col = lane & 31, hi = lane >> 5;

  stage_w128t<512>(mW1, wA0, tid);
  stage_w128t<512>(mW1 + 16384, wA1, tid);
  for (int p = tid; p < 2048; p += 512) {
    int j = p >> 4, kk = p & 15;
    float w = (kk < 6) ? mW1[(256 + kk) * 128 + j] : 0.f;
    wE[j * 16 + kk] = (short)(pkbf(w, 0.f) & 0xffffu);
  }
  if (tid < 128) sb1[tid] = mb1[tid];
  __syncthreads();

  const int T = (E + 31) / 32;
  const int stride = gridDim.x * 8;
  int t = blockIdx.x * 8 + wid;
  if (t >= T) return;

  int p = t * 32 + col;
  int pc = p < E ? p : E - 1;
  i32x4v ra = *(const i32x4v*)(rec + (size_t)pc * 8);
  int ev2 = rec[(size_t)pc * 8 + 4];

  while (t < T) {
    bool va = p < E;
    int s = ra[0], d = ra[1];

    i32x4v bs[8], bd[8];
    #pragma unroll
    for (int kc = 0; kc < 8; ++kc)
      bs[kc] = *(const i32x4v*)(hbf + (size_t)s * 256 + kc * 32 + hi * 16);
    #pragma unroll
    for (int kc = 0; kc < 8; ++kc)
      bd[kc] = *(const i32x4v*)(hbf + (size_t)d * 256 + kc * 32 + hi * 16);

    int tn = t + stride;
    int pn = tn * 32 + col;
    int pcn = pn < E ? pn : E - 1;
    i32x4v nra = *(const i32x4v*)(rec + (size_t)pcn * 8);
    int nev2 = rec[(size_t)pcn * 8 + 4];

    char* rowptr = t1 + (size_t)p * 256;
    #pragma unroll
    for (int g = 0; g < 2; ++g) {
      f32x16 acc2[2];
      #pragma unroll
      for (int j2 = 0; j2 < 2; ++j2)
        #pragma unroll
        for (int r = 0; r < 16; ++r) acc2[j2][r] = 0.f;

      #pragma unroll
      for (int kc = 0; kc < 8; ++kc) {
        bf16x8 bb = __builtin_bit_cast(bf16x8, bs[kc]);
        #pragma unroll
        for (int j2 = 0; j2 < 2; ++j2)
          acc2[j2] = MFMA32(ldsA(wA0, (g * 2 + j2) * 32 + col, kc * 16 + hi * 8), bb, acc2[j2]);
      }
      #pragma unroll
      for (int kc = 0; kc < 8; ++kc) {
        bf16x8 bb = __builtin_bit_cast(bf16x8, bd[kc]);
        #pragma unroll
        for (int j2 = 0; j2 < 2; ++j2)
          acc2[j2] = MFMA32(ldsA(wA1, (g * 2 + j2) * 32 + col, kc * 16 + hi * 8), bb, acc2[j2]);
      }
      {
        i32x4v ev;
        ev[0] = hi ? 0 : ra[2];
        ev[1] = hi ? 0 : ra[3];
        ev[2] = hi ? 0 : ev2;
        ev[3] = 0;
        bf16x8 be = __builtin_bit_cast(bf16x8, ev);
        #pragma unroll
        for (int j2 = 0; j2 < 2; ++j2) {
          bf16x8 af = __builtin_bit_cast(bf16x8,
              *(const i32x4v*)((const char*)wE + ((g * 2 + j2) * 32 + col) * 32 + hi * 16));
          acc2[j2] = MFMA32(af, be, acc2[j2]);
        }
      }
      #pragma unroll
      for (int j2 = 0; j2 < 2; ++j2)
        trans_store1(acc2[j2], sb1, hi, rowptr, va, g * 2 + j2);
    }

    t = tn; p = pn; ra = nra; ev2 = nev2;
  }
}

// Edge layer2 + c-layer; m aggregated IN-KERNEL via sorted-segment scan +
// tail atomics into m_sum[N][128] f32 (no m_ij materialization).
__global__ __launch_bounds__(512, 2)
void kedgeB(const char* __restrict__ buf, const int* __restrict__ rec,
            const float* __restrict__ mW2, const float* __restrict__ mb2,
            const float* __restrict__ cW1, const float* __restrict__ cb1,
            const float* __restrict__ cW2v, const float* __restrict__ cb2,
            float* __restrict__ m_sum, float* __restrict__ coef, int E)
{
  __shared__ short wA2[16384], wA3[16384];
  __shared__ float sb2[128], scb1[128], scw2[128];
  __shared__ float scb2v[1];

  const int tid = threadIdx.x, wid = tid >> 6, lane = tid & 63;
  const int col = lane & 31, hi = lane >> 5;

  stage_w128t<512>(mW2, wA2, tid);
  stage_w128t<512>(cW1, wA3, tid);
  if (tid < 128) {
    sb2[tid] = mb2[tid]; scb1[tid] = cb1[tid]; scw2[tid] = cW2v[tid];
  }
  if (tid == 0) scb2v[0] = cb2[0];
  __syncthreads();

  const int T = (E + 31) / 32;
  const int stride = gridDim.x * 8;
  for (int t = blockIdx.x * 8 + wid; t < T; t += stride) {
    int p = t * 32 + col;
    bool va = p < E;
    int pc = va ? p : E - 1;

    int skey = rec[(size_t)pc * 8];    // src of this slot (sorted)

    i32x4v b[8];
    #pragma unroll
    for (int kc = 0; kc < 8; ++kc)
      b[kc] = *(const i32x4v*)(buf + (size_t)pc * 256 + kc * 32 + hi * 16);

    // neighbor keys for scan/tail (same for all jm groups)
    int nk[5];
    #pragma unroll
    for (int st = 0; st < 5; ++st) {
      int off = 1 << st;
      int sl = (col >= off) ? (lane - off) : lane;
      nk[st] = __shfl(skey, sl);
    }
    int slT = (col == 31) ? lane : (lane + 1);
    int keyNext = __shfl(skey, slT);
    bool tail = (col == 31) || (keyNext != skey);

    i32x4v fr[8];
    #pragma unroll
    for (int g = 0; g < 2; ++g) {
      f32x16 acc2[2];
      #pragma unroll
      for (int j2 = 0; j2 < 2; ++j2)
        #pragma unroll
        for (int r = 0; r < 16; ++r) acc2[j2][r] = 0.f;
      #pragma unroll
      for (int kc = 0; kc < 8; ++kc) {
        bf16x8 bb = __builtin_bit_cast(bf16x8, b[kc]);
        #pragma unroll
        for (int j2 = 0; j2 < 2; ++j2)
          acc2[j2] = MFMA32(ldsA(wA2, (g * 2 + j2) * 32 + col, kc * 16 + hi * 8), bb, acc2[j2]);
      }
      #pragma unroll
      for (int j2 = 0; j2 < 2; ++j2) {
        int jm = g * 2 + j2;
        float v[16];
        #pragma unroll
        for (int r = 0; r < 16; ++r) {
          int rowloc = (r & 3) + 8 * (r >> 2) + 4 * hi;
          v[r] = silu_f(acc2[j2][r] + sb2[jm * 32 + rowloc]);
        }
        frags_from_v(v, hi, fr, jm);
        // segmented inclusive scan over cols (sorted src)
        if (!va)
          #pragma unroll
          for (int r = 0; r < 16; ++r) v[r] = 0.f;
        #pragma unroll
        for (int st = 0; st < 5; ++st) {
          int off = 1 << st;
          int sl = (col >= off) ? (lane - off) : lane;
          bool ok = (col >= off) && (nk[st] == skey);
          #pragma unroll
          for (int r = 0; r < 16; ++r) {
            float nv = __shfl(v[r], sl);
            if (ok) v[r] += nv;
          }
        }
        if (tail) {
          float* dstp = m_sum + (size_t)skey * 128 + jm * 32;
          #pragma unroll
          for (int r = 0; r < 16; ++r) {
            int rowloc = (r & 3) + 8 * (r >> 2) + 4 * hi;
            unsafeAtomicAdd(dstp + rowloc, v[r]);
          }
        }
      }
    }

    // c-layer
    float part = 0.f;
    #pragma unroll
    for (int g = 0; g < 2; ++g) {
      f32x16 acc2[2];
      #pragma unroll
      for (int j2 = 0; j2 < 2; ++j2)
        #pragma unroll
        for (int r = 0; r < 16; ++r) acc2[j2][r] = 0.f;
      #pragma unroll
      for (int kc = 0; kc < 8; ++kc) {
        bf16x8 bb = __builtin_bit_cast(bf16x8, fr[kc]);
        #pragma unroll
        for (int j2 = 0; j2 < 2; ++j2)
          acc2[j2] = MFMA32(ldsA(wA3, (g * 2 + j2) * 32 + col, kc * 16 + hi * 8), bb, acc2[j2]);
      }
      #pragma unroll
      for (int j2 = 0; j2 < 2; ++j2) {
        int jm = g * 2 + j2;
        #pragma unroll
        for (int r = 0; r < 16; ++r) {
          int rowloc = (r & 3) + 8 * (r >> 2) + 4 * hi;
          part += silu_f(acc2[j2][r] + scb1[jm * 32 + rowloc]) * scw2[jm * 32 + rowloc];
        }
      }
    }
    part += __shfl_xor(part, 32);
    float cf = tanh_f(part + scb2v[0]);
    if (va && hi == 0) coef[p] = cf;
  }
}

// x epilogue only: one thread per node.
__global__ __launch_bounds__(256)
void kaggx(const int* __restrict__ row_start, const int* __restrict__ cnt,
           const float* __restrict__ coef, const int* __restrict__ rec,
           const float* __restrict__ x, float* __restrict__ outX, int N)
{
  int n = blockIdx.x * 256 + threadIdx.x;
  if (n >= N) return;
  int st = row_start[n], c = cnt[n];
  float x0 = x[(size_t)n * 3], x1 = x[(size_t)n * 3 + 1], x2 = x[(size_t)n * 3 + 2];
  float dx = 0.f, dy = 0.f, dz = 0.f;
  for (int k = 0; k < c; ++k) {
    float cf = coef[st + k];
    int dn = rec[(size_t)(st + k) * 8 + 1];
    dx += (x0 - x[(size_t)dn * 3])     * cf;
    dy += (x1 - x[(size_t)dn * 3 + 1]) * cf;
    dz += (x2 - x[(size_t)dn * 3 + 2]) * cf;
  }
  float inv = 1.f / fmaxf((float)c, 1.f);
  outX[(size_t)n * 3]     = x0 + dx * inv;
  outX[(size_t)n * 3 + 1] = x1 + dy * inv;
  outX[(size_t)n * 3 + 2] = x2 + dz * inv;
}

// Node MLP layer1: t1h = silu([h | m_sum/deg] . hW1 + b1)
__global__ __launch_bounds__(512, 2)
void knode1(const char* __restrict__ hbf, const float* __restrict__ m_sum,
            const int* __restrict__ cnt,
            const float* __restrict__ hW1, const float* __restrict__ hb1,
            char* __restrict__ t1h, int N)
{
  __shared__ short wA0[16384], wA1[16384];
  __shared__ float sb1[128];
  const int tid = threadIdx.x, wid = tid >> 6, lane = tid & 63;
  const int col = lane & 31, hi = lane >> 5;
  stage_w128t<512>(hW1, wA0, tid);
  stage_w128t<512>(hW1 + 16384, wA1, tid);
  if (tid < 128) sb1[tid] = hb1[tid];
  __syncthreads();

  int T = (N + 31) / 32;
  int t = blockIdx.x * 8 + wid;
  if (t >= T) return;
  int n = t * 32 + col;
  bool va = n < N;
  int nc = va ? n : N - 1;
  float inv = 1.f / fmaxf((float)cnt[nc], 1.f);

  i32x4v bh[8], bm[8];
  #pragma unroll
  for (int kc = 0; kc < 8; ++kc)
    bh[kc] = *(const i32x4v*)(hbf + (size_t)nc * 256 + kc * 32 + hi * 16);
  const float4* m4 = (const float4*)m_sum;
  #pragma unroll
  for (int kc = 0; kc < 8; ++kc) {
    // dims [kc*16 + hi*8, +8) of the 128-f32 row = float4 index kc*4 + hi*2
    float4 a  = m4[(size_t)nc * 32 + kc * 4 + hi * 2 + 0];
    float4 bq = m4[(size_t)nc * 32 + kc * 4 + hi * 2 + 1];
    i32x4v w;
    w[0] = (int)pkbf(a.x * inv, a.y * inv);
    w[1] = (int)pkbf(a.z * inv, a.w * inv);
    w[2] = (int)pkbf(bq.x * inv, bq.y * inv);
    w[3] = (int)pkbf(bq.z * inv, bq.w * inv);
    bm[kc] = w;
  }

  char* rowptr = t1h + (size_t)n * 256;
  #pragma unroll
  for (int g = 0; g < 2; ++g) {
    f32x16 acc2[2];
    #pragma unroll
    for (int j2 = 0; j2 < 2; ++j2)
      #pragma unroll
      for (int r = 0; r < 16; ++r) acc2[j2][r] = 0.f;
    #pragma unroll
    for (int kc = 0; kc < 8; ++kc) {
      bf16x8 bb = __builtin_bit_cast(bf16x8, bh[kc]);
      #pragma unroll
      for (int j2 = 0; j2 < 2; ++j2)
        acc2[j2] = MFMA32(ldsA(wA0, (g * 2 + j2) * 32 + col, kc * 16 + hi * 8), bb, acc2[j2]);
    }
    #pragma unroll
    for (int kc = 0; kc < 8; ++kc) {
      bf16x8 bb = __builtin_bit_cast(bf16x8, bm[kc]);
      #pragma unroll
      for (int j2 = 0; j2 < 2; ++j2)
        acc2[j2] = MFMA32(ldsA(wA1, (g * 2 + j2) * 32 + col, kc * 16 + hi * 8), bb, acc2[j2]);
    }
    #pragma unroll
    for (int j2 = 0; j2 < 2; ++j2)
      trans_store1(acc2[j2], sb1, hi, rowptr, va, g * 2 + j2);
  }
}

// Node MLP layer2 + residual.
__global__ __launch_bounds__(512, 2)
void knode2(const char* __restrict__ t1h, const float* __restrict__ hW2,
            const float* __restrict__ hb2, const float* __restrict__ h,
            float* __restrict__ outH, int N)
{
  __shared__ short wA0[16384];
  __shared__ float sb2[128];
  const int tid = threadIdx.x, wid = tid >> 6, lane = tid & 63;
  const int col = lane & 31, hi = lane >> 5;
  stage_w128t<512>(hW2, wA0, tid);
  if (tid < 128) sb2[tid] = hb2[tid];
  __syncthreads();

  int T = (N + 31) / 32;
  int t = blockIdx.x * 8 + wid;
  if (t >= T) return;
  int n = t * 32 + col;
  bool va = n < N;
  int nc = va ? n : N - 1;

  i32x4v b[8];
  #pragma unroll
  for (int kc = 0; kc < 8; ++kc)
    b[kc] = *(const i32x4v*)(t1h + (size_t)nc * 256 + kc * 32 + hi * 16);

  const float4* h4 = (const float4*)h;
  #pragma unroll
  for (int g = 0; g < 2; ++g) {
    f32x16 acc2[2];
    #pragma unroll
    for (int j2 = 0; j2 < 2; ++j2)
      #pragma unroll
      for (int r = 0; r < 16; ++r) acc2[j2][r] = 0.f;
    #pragma unroll
    for (int kc = 0; kc < 8; ++kc) {
      bf16x8 bb = __builtin_bit_cast(bf16x8, b[kc]);
      #pragma unroll
      for (int j2 = 0; j2 < 2; ++j2)
        acc2[j2] = MFMA32(ldsA(wA0, (g * 2 + j2) * 32 + col, kc * 16 + hi * 8), bb, acc2[j2]);
    }
    #pragma unroll
    for (int j2 = 0; j2 < 2; ++j2) {
      int jm = g * 2 + j2;
      #pragma unroll
      for (int rq = 0; rq < 4; ++rq) {
        int j0 = jm * 32 + rq * 8 + hi * 4;
        float4 hv = h4[(size_t)nc * 32 + (j0 >> 2)];
        float4 o;
        o.x = hv.x + acc2[j2][rq * 4 + 0] + sb2[j0 + 0];
        o.y = hv.y + acc2[j2][rq * 4 + 1] + sb2[j0 + 1];
        o.z = hv.z + acc2[j2][rq * 4 + 2] + sb2[j0 + 2];
        o.w = hv.w + acc2[j2][rq * 4 + 3] + sb2[j0 + 3];
        if (va) ((float4*)outH)[(size_t)nc * 32 + (j0 >> 2)] = o;
      }
    }
  }
}

// ===================== LAUNCH =====================

extern "C" void kernel_launch(void* const* d_in, const int* in_sizes, int n_in,
                              void* d_out, int out_size, void* d_ws, size_t ws_size,
                              hipStream_t stream) {
  const float* h    = (const float*)d_in[0];
  const float* x    = (const float*)d_in[1];
  const int*   src  = (const int*)d_in[2];
  const int*   dst  = (const int*)d_in[3];
  const float* dist = (const float*)d_in[4];
  const float* bpp  = (const float*)d_in[5];
  const float* msa  = (const float*)d_in[6];
  const float* chem = (const float*)d_in[7];
  const float* rel  = (const float*)d_in[8];
  const float* cbm  = (const float*)d_in[9];
  const float* mW1  = (const float*)d_in[10];
  const float* mb1  = (const float*)d_in[11];
  const float* mW2  = (const float*)d_in[12];
  const float* mb2  = (const float*)d_in[13];
  const float* hW1  = (const float*)d_in[14];
  const float* hb1  = (const float*)d_in[15];
  const float* hW2  = (const float*)d_in[16];
  const float* hb2  = (const float*)d_in[17];
  const float* cW1  = (const float*)d_in[18];
  const float* cb1  = (const float*)d_in[19];
  const float* cW2  = (const float*)d_in[20];
  const float* cb2  = (const float*)d_in[21];

  int N = in_sizes[0] / 128;
  int E = in_sizes[2];

  size_t off = 0;
  auto A = [&](size_t b) { size_t o = off; off += (b + 255) & ~(size_t)255; return o; };
  size_t o_cnt  = A((size_t)N * 4);
  size_t o_rs   = A((size_t)N * 4);
  size_t o_head = A((size_t)N * 4);
  size_t o_rec  = A((size_t)E * 32);
  size_t o_coef = A((size_t)E * 4);
  size_t o_bs   = A(1024);
  size_t o_hbf  = A((size_t)N * 256);
  size_t o_msum = A((size_t)N * 512);   // f32 [N][128]
  size_t o_big  = A((size_t)E * 256);   // t1 -> t1h (reused)

  char* W = (char*)d_ws;
  int*   cnt32 = (int*)(W + o_cnt);
  int*   rs    = (int*)(W + o_rs);
  int*   head  = (int*)(W + o_head);
  int*   rec   = (int*)(W + o_rec);
  float* coef  = (float*)(W + o_coef);
  int*   bsums = (int*)(W + o_bs);
  char*  hbf   = W + o_hbf;
  float* msum  = (float*)(W + o_msum);
  char*  big   = W + o_big;

  hipMemsetAsync(cnt32, 0, (size_t)N * 4, stream);
  hipMemsetAsync(msum, 0, (size_t)N * 512, stream);
  kconv<<<(N * 16 + 255) / 256, 256, 0, stream>>>(h, hbf, N * 16);
  khist<<<(E + 255) / 256, 256, 0, stream>>>(src, cnt32, E);
  int nb = (N + 1023) / 1024;
  kscan1<<<nb, 1024, 0, stream>>>(cnt32, rs, bsums, N);
  kscan2<<<1, 64, 0, stream>>>(bsums, nb);
  kscan3<<<nb, 1024, 0, stream>>>(bsums, rs, head, N);
  kscatter<<<(E + 255) / 256, 256, 0, stream>>>(src, dst, dist, bpp, msa, chem, rel, cbm,
                                                head, rec, E);
  kedgeA<<<512, 512, 0, stream>>>(hbf, rec, mW1, mb1, big, E);
  kedgeB<<<512, 512, 0, stream>>>(big, rec, mW2, mb2, cW1, cb1, cW2, cb2,
                                  msum, coef, E);
  kaggx<<<(N + 255) / 256, 256, 0, stream>>>(rs, cnt32, coef, rec, x,
                                             (float*)d_out + (size_t)N * 128, N);
  int tb = ((N + 31) / 32 + 7) / 8;
  knode1<<<tb, 512, 0, stream>>>(hbf, msum, cnt32, hW1, hb1, big, N);
  knode2<<<tb, 512, 0, stream>>>(big, hW2, hb2, h, (float*)d_out, N);
}

// Round 14
// 647.317 us; speedup vs baseline: 1.5380x; 1.1555x over previous
//
#include <hip/hip_runtime.h>
#include <hip/hip_bf16.h>

typedef short bf16x8 __attribute__((ext_vector_type(8)));
typedef float f32x16 __attribute__((ext_vector_type(16)));
typedef int   i32x4v __attribute__((ext_vector_type(4)));
typedef unsigned u32;

#define MFMA32(a,b,c) __builtin_amdgcn_mfma_f32_32x32x16_bf16((a),(b),(c),0,0,0)

__device__ __forceinline__ u32 pkbf(float x, float y) {
  union { u32 u; __hip_bfloat16 h[2]; } t;
  t.h[0] = __float2bfloat16(x);
  t.h[1] = __float2bfloat16(y);
  return t.u;
}
__device__ __forceinline__ float bf2f(u32 lo16) {
  union { u32 u; float f; } t; t.u = lo16 << 16; return t.f;
}
__device__ __forceinline__ float silu_f(float v) { return v / (1.f + __expf(-v)); }
__device__ __forceinline__ float tanh_f(float v) {
  float e = __expf(2.f * fabsf(v));
  float t = 1.f - 2.f / (e + 1.f);
  return copysignf(t, v);
}

template<int NT>
__device__ __forceinline__ void stage_w128t(const float* __restrict__ W, short* wA, int tid) {
  for (int p = tid; p < 8192; p += NT) {
    int j = p & 127;
    int k = (p >> 7) << 1;
    u32 u = pkbf(W[k * 128 + j], W[k * 128 + 128 + j]);
    int off = j * 256 + (((k >> 3) ^ (j & 15)) << 4) + ((k & 7) << 1);
    *(u32*)((char*)wA + off) = u;
  }
}
__device__ __forceinline__ bf16x8 ldsA(const short* wA, int j, int kbase) {
  int off = j * 256 + (((kbase >> 3) ^ (j & 15)) << 4);
  return __builtin_bit_cast(bf16x8, *(const i32x4v*)((const char*)wA + off));
}

// Store one jm-block of a row as 2x16B chunks per lane (hi-pair exchange),
// NON-TEMPORAL (workspace streaming buffers only).
__device__ __forceinline__ void row_chunks(u32 p0, u32 p1, u32 p2, u32 p3,
                                           u32 p4, u32 p5, u32 p6, u32 p7,
                                           int hi, char* rowptr, int jm) {
  u32 x0 = (u32)__shfl_xor((int)(hi ? p0 : p4), 32);
  u32 x1 = (u32)__shfl_xor((int)(hi ? p1 : p5), 32);
  u32 x2 = (u32)__shfl_xor((int)(hi ? p2 : p6), 32);
  u32 x3 = (u32)__shfl_xor((int)(hi ? p3 : p7), 32);
  i32x4v c0, c1;
  if (hi) {
    c0[0] = (int)x0; c0[1] = (int)x1; c0[2] = (int)p4; c0[3] = (int)p5;
    c1[0] = (int)x2; c1[1] = (int)x3; c1[2] = (int)p6; c1[3] = (int)p7;
  } else {
    c0[0] = (int)p0; c0[1] = (int)p1; c0[2] = (int)x0; c0[3] = (int)x1;
    c1[0] = (int)p2; c1[1] = (int)p3; c1[2] = (int)x2; c1[3] = (int)x3;
  }
  __builtin_nontemporal_store(c0, (i32x4v*)(rowptr + jm * 64 + hi * 32));
  __builtin_nontemporal_store(c1, (i32x4v*)(rowptr + jm * 64 + hi * 32 + 16));
}

// One jm (global index) of C-layout -> silu(+bias) -> row store.
__device__ __forceinline__ void trans_store1(const f32x16& a, const float* bias, int hi,
                                             char* rowptr, bool va, int jm) {
  float v[16];
  #pragma unroll
  for (int r = 0; r < 16; ++r) {
    int rowloc = (r & 3) + 8 * (r >> 2) + 4 * hi;
    v[r] = silu_f(a[r] + bias[jm * 32 + rowloc]);
  }
  u32 p0 = pkbf(v[0], v[1]),  p1 = pkbf(v[2], v[3]);
  u32 p2 = pkbf(v[4], v[5]),  p3 = pkbf(v[6], v[7]);
  u32 p4 = pkbf(v[8], v[9]),  p5 = pkbf(v[10], v[11]);
  u32 p6 = pkbf(v[12], v[13]), p7 = pkbf(v[14], v[15]);
  if (va) row_chunks(p0, p1, p2, p3, p4, p5, p6, p7, hi, rowptr, jm);
}

// One jm: C-layout -> silu(+bias) -> B-frags (fr[jm*2], fr[jm*2+1]) + row store.
__device__ __forceinline__ void trans_frag1(const f32x16& a, const float* bias, int hi,
                                            i32x4v* fr, char* rowptr, bool va, int jm) {
  float v[16];
  #pragma unroll
  for (int r = 0; r < 16; ++r) {
    int rowloc = (r & 3) + 8 * (r >> 2) + 4 * hi;
    v[r] = silu_f(a[r] + bias[jm * 32 + rowloc]);
  }
  u32 p0 = pkbf(v[0], v[1]),  p1 = pkbf(v[2], v[3]);
  u32 p2 = pkbf(v[4], v[5]),  p3 = pkbf(v[6], v[7]);
  u32 p4 = pkbf(v[8], v[9]),  p5 = pkbf(v[10], v[11]);
  u32 p6 = pkbf(v[12], v[13]), p7 = pkbf(v[14], v[15]);
  {
    u32 g1 = (u32)__shfl_xor((int)(hi ? p0 : p2), 32);
    u32 g2 = (u32)__shfl_xor((int)(hi ? p1 : p3), 32);
    i32x4v w;
    w[0] = hi ? (int)g1 : (int)p0;
    w[1] = hi ? (int)g2 : (int)p1;
    w[2] = hi ? (int)p2 : (int)g1;
    w[3] = hi ? (int)p3 : (int)g2;
    fr[jm * 2] = w;
    u32 g1b = (u32)__shfl_xor((int)(hi ? p4 : p6), 32);
    u32 g2b = (u32)__shfl_xor((int)(hi ? p5 : p7), 32);
    i32x4v w2;
    w2[0] = hi ? (int)g1b : (int)p4;
    w2[1] = hi ? (int)g2b : (int)p5;
    w2[2] = hi ? (int)p6 : (int)g1b;
    w2[3] = hi ? (int)p7 : (int)g2b;
    fr[jm * 2 + 1] = w2;
  }
  if (va) row_chunks(p0, p1, p2, p3, p4, p5, p6, p7, hi, rowptr, jm);
}

// ===================== PIPELINE =====================

__global__ void kconv(const float* __restrict__ h, char* __restrict__ hbf, int total16) {
  int i = blockIdx.x * 256 + threadIdx.x;
  if (i >= total16) return;
  const float4* h4 = (const float4*)h;
  float4 a = h4[(size_t)i * 2], b = h4[(size_t)i * 2 + 1];
  i32x4v w;
  w[0] = (int)pkbf(a.x, a.y); w[1] = (int)pkbf(a.z, a.w);
  w[2] = (int)pkbf(b.x, b.y); w[3] = (int)pkbf(b.z, b.w);
  *(i32x4v*)(hbf + (size_t)i * 16) = w;
}

__global__ void khist(const int* __restrict__ src, int* __restrict__ cnt, int E) {
  int e = blockIdx.x * 256 + threadIdx.x;
  if (e < E) atomicAdd(&cnt[src[e]], 1);
}

__global__ void kscan1(const int* __restrict__ cnt, int* __restrict__ part,
                       int* __restrict__ bsums, int N) {
  __shared__ int sh[1024];
  int tid = threadIdx.x, i = blockIdx.x * 1024 + tid;
  int v = (i < N) ? cnt[i] : 0;
  sh[tid] = v; __syncthreads();
  for (int off = 1; off < 1024; off <<= 1) {
    int t = (tid >= off) ? sh[tid - off] : 0;
    __syncthreads();
    sh[tid] += t;
    __syncthreads();
  }
  if (i < N) part[i] = sh[tid] - v;
  if (tid == 1023) bsums[blockIdx.x] = sh[1023];
}

__global__ void kscan2(int* __restrict__ bsums, int nb) {
  __shared__ int sh[64];
  int tid = threadIdx.x;
  int v = (tid < nb) ? bsums[tid] : 0;
  sh[tid] = v; __syncthreads();
  for (int off = 1; off < 64; off <<= 1) {
    int t = (tid >= off) ? sh[tid - off] : 0;
    __syncthreads();
    sh[tid] += t;
    __syncthreads();
  }
  if (tid < nb) bsums[tid] = sh[tid] - v;
}

__global__ void kscan3(const int* __restrict__ bsums, int* __restrict__ part,
                       int* __restrict__ head, int N) {
  int i = blockIdx.x * 1024 + threadIdx.x;
  if (i < N) {
    int v = part[i] + bsums[blockIdx.x];
    part[i] = v;
    head[i] = v;
  }
}

__global__ void kscatter(const int* __restrict__ src, const int* __restrict__ dst,
                         const float* __restrict__ dist, const float* __restrict__ bpp,
                         const float* __restrict__ msa, const float* __restrict__ chem,
                         const float* __restrict__ rel, const float* __restrict__ cbm,
                         int* __restrict__ head, int* __restrict__ rec, int E) {
  int e = blockIdx.x * 256 + threadIdx.x;
  if (e >= E) return;
  int s = src[e];
  int p = atomicAdd(&head[s], 1);
  float q = dist[e];
  i32x4v a;
  a[0] = s;
  a[1] = dst[e];
  a[2] = (int)pkbf(q * q, bpp[e]);
  a[3] = (int)pkbf(msa[e], chem[e]);
  *(i32x4v*)(rec + (size_t)p * 8) = a;
  rec[(size_t)p * 8 + 4] = (int)pkbf(rel[e], cbm[e]);
}

// Edge layer1: t1 = silu(feat . W1 + b1). (r8-proven body, NT t1 stores)
__global__ __launch_bounds__(512, 2)
void kedgeA(const char* __restrict__ hbf, const int* __restrict__ rec,
            const float* __restrict__ mW1, const float* __restrict__ mb1,
            char* __restrict__ t1, int E)
{
  __shared__ short wA0[16384], wA1[16384];
  __shared__ short wE[2048];
  __shared__ float sb1[128];

  const int tid = threadIdx.x, wid = tid >> 6, lane = tid & 63;
  const int col = lane & 31, hi = lane >> 5;

  stage_w128t<512>(mW1, wA0, tid);
  stage_w128t<512>(mW1 + 16384, wA1, tid);
  for (int p = tid; p < 2048; p += 512) {
    int j = p >> 4, kk = p & 15;
    float w = (kk < 6) ? mW1[(256 + kk) * 128 + j] : 0.f;
    wE[j * 16 + kk] = (short)(pkbf(w, 0.f) & 0xffffu);
  }
  if (tid < 128) sb1[tid] = mb1[tid];
  __syncthreads();

  const int T = (E + 31) / 32;
  const int stride = gridDim.x * 8;
  int t = blockIdx.x * 8 + wid;
  if (t >= T) return;

  int p = t * 32 + col;
  int pc = p < E ? p : E - 1;
  i32x4v ra = *(const i32x4v*)(rec + (size_t)pc * 8);
  int ev2 = rec[(size_t)pc * 8 + 4];

  while (t < T) {
    bool va = p < E;
    int s = ra[0], d = ra[1];

    i32x4v bs[8], bd[8];
    #pragma unroll
    for (int kc = 0; kc < 8; ++kc)
      bs[kc] = *(const i32x4v*)(hbf + (size_t)s * 256 + kc * 32 + hi * 16);
    #pragma unroll
    for (int kc = 0; kc < 8; ++kc)
      bd[kc] = *(const i32x4v*)(hbf + (size_t)d * 256 + kc * 32 + hi * 16);

    int tn = t + stride;
    int pn = tn * 32 + col;
    int pcn = pn < E ? pn : E - 1;
    i32x4v nra = *(const i32x4v*)(rec + (size_t)pcn * 8);
    int nev2 = rec[(size_t)pcn * 8 + 4];

    char* rowptr = t1 + (size_t)p * 256;
    #pragma unroll
    for (int g = 0; g < 2; ++g) {
      f32x16 acc2[2];
      #pragma unroll
      for (int j2 = 0; j2 < 2; ++j2)
        #pragma unroll
        for (int r = 0; r < 16; ++r) acc2[j2][r] = 0.f;

      #pragma unroll
      for (int kc = 0; kc < 8; ++kc) {
        bf16x8 bb = __builtin_bit_cast(bf16x8, bs[kc]);
        #pragma unroll
        for (int j2 = 0; j2 < 2; ++j2)
          acc2[j2] = MFMA32(ldsA(wA0, (g * 2 + j2) * 32 + col, kc * 16 + hi * 8), bb, acc2[j2]);
      }
      #pragma unroll
      for (int kc = 0; kc < 8; ++kc) {
        bf16x8 bb = __builtin_bit_cast(bf16x8, bd[kc]);
        #pragma unroll
        for (int j2 = 0; j2 < 2; ++j2)
          acc2[j2] = MFMA32(ldsA(wA1, (g * 2 + j2) * 32 + col, kc * 16 + hi * 8), bb, acc2[j2]);
      }
      {
        i32x4v ev;
        ev[0] = hi ? 0 : ra[2];
        ev[1] = hi ? 0 : ra[3];
        ev[2] = hi ? 0 : ev2;
        ev[3] = 0;
        bf16x8 be = __builtin_bit_cast(bf16x8, ev);
        #pragma unroll
        for (int j2 = 0; j2 < 2; ++j2) {
          bf16x8 af = __builtin_bit_cast(bf16x8,
              *(const i32x4v*)((const char*)wE + ((g * 2 + j2) * 32 + col) * 32 + hi * 16));
          acc2[j2] = MFMA32(af, be, acc2[j2]);
        }
      }
      #pragma unroll
      for (int j2 = 0; j2 < 2; ++j2)
        trans_store1(acc2[j2], sb1, hi, rowptr, va, g * 2 + j2);
    }

    t = tn; p = pn; ra = nra; ev2 = nev2;
  }
}

// Edge layer2 + c-layer: pure streaming over slots (r8 body, NT loads+stores).
__global__ __launch_bounds__(512, 2)
void kedgeB(char* buf,
            const float* __restrict__ mW2, const float* __restrict__ mb2,
            const float* __restrict__ cW1, const float* __restrict__ cb1,
            const float* __restrict__ cW2v, const float* __restrict__ cb2,
            float* __restrict__ coef, int E)
{
  __shared__ short wA2[16384], wA3[16384];
  __shared__ float sb2[128], scb1[128], scw2[128];
  __shared__ float scb2v[1];

  const int tid = threadIdx.x, wid = tid >> 6, lane = tid & 63;
  const int col = lane & 31, hi = lane >> 5;

  stage_w128t<512>(mW2, wA2, tid);
  stage_w128t<512>(cW1, wA3, tid);
  if (tid < 128) {
    sb2[tid] = mb2[tid]; scb1[tid] = cb1[tid]; scw2[tid] = cW2v[tid];
  }
  if (tid == 0) scb2v[0] = cb2[0];
  __syncthreads();

  const int T = (E + 31) / 32;
  const int stride = gridDim.x * 8;
  for (int t = blockIdx.x * 8 + wid; t < T; t += stride) {
    int p = t * 32 + col;
    bool va = p < E;
    int pc = va ? p : E - 1;

    i32x4v b[8];
    #pragma unroll
    for (int kc = 0; kc < 8; ++kc)
      b[kc] = __builtin_nontemporal_load(
          (const i32x4v*)(buf + (size_t)pc * 256 + kc * 32 + hi * 16));

    char* rowptr = buf + (size_t)p * 256;
    i32x4v fr[8];
    #pragma unroll
    for (int g = 0; g < 2; ++g) {
      f32x16 acc2[2];
      #pragma unroll
      for (int j2 = 0; j2 < 2; ++j2)
        #pragma unroll
        for (int r = 0; r < 16; ++r) acc2[j2][r] = 0.f;
      #pragma unroll
      for (int kc = 0; kc < 8; ++kc) {
        bf16x8 bb = __builtin_bit_cast(bf16x8, b[kc]);
        #pragma unroll
        for (int j2 = 0; j2 < 2; ++j2)
          acc2[j2] = MFMA32(ldsA(wA2, (g * 2 + j2) * 32 + col, kc * 16 + hi * 8), bb, acc2[j2]);
      }
      #pragma unroll
      for (int j2 = 0; j2 < 2; ++j2)
        trans_frag1(acc2[j2], sb2, hi, fr, rowptr, va, g * 2 + j2);
    }

    float part = 0.f;
    #pragma unroll
    for (int g = 0; g < 2; ++g) {
      f32x16 acc2[2];
      #pragma unroll
      for (int j2 = 0; j2 < 2; ++j2)
        #pragma unroll
        for (int r = 0; r < 16; ++r) acc2[j2][r] = 0.f;
      #pragma unroll
      for (int kc = 0; kc < 8; ++kc) {
        bf16x8 bb = __builtin_bit_cast(bf16x8, fr[kc]);
        #pragma unroll
        for (int j2 = 0; j2 < 2; ++j2)
          acc2[j2] = MFMA32(ldsA(wA3, (g * 2 + j2) * 32 + col, kc * 16 + hi * 8), bb, acc2[j2]);
      }
      #pragma unroll
      for (int j2 = 0; j2 < 2; ++j2) {
        int jm = g * 2 + j2;
        #pragma unroll
        for (int r = 0; r < 16; ++r) {
          int rowloc = (r & 3) + 8 * (r >> 2) + 4 * hi;
          part += silu_f(acc2[j2][r] + scb1[jm * 32 + rowloc]) * scw2[jm * 32 + rowloc];
        }
      }
    }
    part += __shfl_xor(part, 32);
    float cf = tanh_f(part + scb2v[0]);
    if (va && hi == 0) coef[p] = cf;
  }
}

// m-sum only: 16 threads per node over sorted slots (NT m_ij loads).
__global__ __launch_bounds__(256)
void kagg(const char* __restrict__ m_ij, const int* __restrict__ row_start,
          const int* __restrict__ cnt, char* __restrict__ mibf, int N)
{
  int n = blockIdx.x * 16 + (threadIdx.x >> 4);
  int t = threadIdx.x & 15;
  if (n >= N) return;
  int st = row_start[n], c = cnt[n];
  float a[8] = {0.f, 0.f, 0.f, 0.f, 0.f, 0.f, 0.f, 0.f};
  for (int k = 0; k < c; ++k) {
    i32x4v u = __builtin_nontemporal_load(
        (const i32x4v*)(m_ij + (size_t)(st + k) * 256 + t * 16));
    #pragma unroll
    for (int q = 0; q < 4; ++q) {
      u32 w = (u32)u[q];
      a[q * 2]     += bf2f(w & 0xffffu);
      a[q * 2 + 1] += bf2f(w >> 16);
    }
  }
  float inv = 1.f / fmaxf((float)c, 1.f);
  i32x4v o;
  #pragma unroll
  for (int q = 0; q < 4; ++q) o[q] = (int)pkbf(a[q * 2] * inv, a[q * 2 + 1] * inv);
  *(i32x4v*)(mibf + (size_t)n * 256 + t * 16) = o;
}

// x epilogue: one thread per node.
__global__ __launch_bounds__(256)
void kaggx(const int* __restrict__ row_start, const int* __restrict__ cnt,
           const float* __restrict__ coef, const int* __restrict__ rec,
           const float* __restrict__ x, float* __restrict__ outX, int N)
{
  int n = blockIdx.x * 256 + threadIdx.x;
  if (n >= N) return;
  int st = row_start[n], c = cnt[n];
  float x0 = x[(size_t)n * 3], x1 = x[(size_t)n * 3 + 1], x2 = x[(size_t)n * 3 + 2];
  float dx = 0.f, dy = 0.f, dz = 0.f;
  for (int k = 0; k < c; ++k) {
    float cf = coef[st + k];
    int dn = rec[(size_t)(st + k) * 8 + 1];
    dx += (x0 - x[(size_t)dn * 3])     * cf;
    dy += (x1 - x[(size_t)dn * 3 + 1]) * cf;
    dz += (x2 - x[(size_t)dn * 3 + 2]) * cf;
  }
  float inv = 1.f / fmaxf((float)c, 1.f);
  outX[(size_t)n * 3]     = x0 + dx * inv;
  outX[(size_t)n * 3 + 1] = x1 + dy * inv;
  outX[(size_t)n * 3 + 2] = x2 + dz * inv;
}

// Node MLP layer1: t1h = silu([h | m_i] . hW1 + b1)
__global__ __launch_bounds__(512, 2)
void knode1(const char* __restrict__ hbf, const char* __restrict__ mibf,
            const float* __restrict__ hW1, const float* __restrict__ hb1,
            char* __restrict__ t1h, int N)
{
  __shared__ short wA0[16384], wA1[16384];
  __shared__ float sb1[128];
  const int tid = threadIdx.x, wid = tid >> 6, lane = tid & 63;
  const int col = lane & 31, hi = lane >> 5;
  stage_w128t<512>(hW1, wA0, tid);
  stage_w128t<512>(hW1 + 16384, wA1, tid);
  if (tid < 128) sb1[tid] = hb1[tid];
  __syncthreads();

  int T = (N + 31) / 32;
  int t = blockIdx.x * 8 + wid;
  if (t >= T) return;
  int n = t * 32 + col;
  bool va = n < N;
  int nc = va ? n : N - 1;

  i32x4v bh[8], bm[8];
  #pragma unroll
  for (int kc = 0; kc < 8; ++kc)
    bh[kc] = *(const i32x4v*)(hbf + (size_t)nc * 256 + kc * 32 + hi * 16);
  #pragma unroll
  for (int kc = 0; kc < 8; ++kc)
    bm[kc] = *(const i32x4v*)(mibf + (size_t)nc * 256 + kc * 32 + hi * 16);

  char* rowptr = t1h + (size_t)n * 256;
  #pragma unroll
  for (int g = 0; g < 2; ++g) {
    f32x16 acc2[2];
    #pragma unroll
    for (int j2 = 0; j2 < 2; ++j2)
      #pragma unroll
      for (int r = 0; r < 16; ++r) acc2[j2][r] = 0.f;
    #pragma unroll
    for (int kc = 0; kc < 8; ++kc) {
      bf16x8 bb = __builtin_bit_cast(bf16x8, bh[kc]);
      #pragma unroll
      for (int j2 = 0; j2 < 2; ++j2)
        acc2[j2] = MFMA32(ldsA(wA0, (g * 2 + j2) * 32 + col, kc * 16 + hi * 8), bb, acc2[j2]);
    }
    #pragma unroll
    for (int kc = 0; kc < 8; ++kc) {
      bf16x8 bb = __builtin_bit_cast(bf16x8, bm[kc]);
      #pragma unroll
      for (int j2 = 0; j2 < 2; ++j2)
        acc2[j2] = MFMA32(ldsA(wA1, (g * 2 + j2) * 32 + col, kc * 16 + hi * 8), bb, acc2[j2]);
    }
    #pragma unroll
    for (int j2 = 0; j2 < 2; ++j2)
      trans_store1(acc2[j2], sb1, hi, rowptr, va, g * 2 + j2);
  }
}

// Node MLP layer2 + residual (NT t1h loads).
__global__ __launch_bounds__(512, 2)
void knode2(const char* __restrict__ t1h, const float* __restrict__ hW2,
            const float* __restrict__ hb2, const float* __restrict__ h,
            float* __restrict__ outH, int N)
{
  __shared__ short wA0[16384];
  __shared__ float sb2[128];
  const int tid = threadIdx.x, wid = tid >> 6, lane = tid & 63;
  const int col = lane & 31, hi = lane >> 5;
  stage_w128t<512>(hW2, wA0, tid);
  if (tid < 128) sb2[tid] = hb2[tid];
  __syncthreads();

  int T = (N + 31) / 32;
  int t = blockIdx.x * 8 + wid;
  if (t >= T) return;
  int n = t * 32 + col;
  bool va = n < N;
  int nc = va ? n : N - 1;

  i32x4v b[8];
  #pragma unroll
  for (int kc = 0; kc < 8; ++kc)
    b[kc] = __builtin_nontemporal_load(
        (const i32x4v*)(t1h + (size_t)nc * 256 + kc * 32 + hi * 16));

  const float4* h4 = (const float4*)h;
  #pragma unroll
  for (int g = 0; g < 2; ++g) {
    f32x16 acc2[2];
    #pragma unroll
    for (int j2 = 0; j2 < 2; ++j2)
      #pragma unroll
      for (int r = 0; r < 16; ++r) acc2[j2][r] = 0.f;
    #pragma unroll
    for (int kc = 0; kc < 8; ++kc) {
      bf16x8 bb = __builtin_bit_cast(bf16x8, b[kc]);
      #pragma unroll
      for (int j2 = 0; j2 < 2; ++j2)
        acc2[j2] = MFMA32(ldsA(wA0, (g * 2 + j2) * 32 + col, kc * 16 + hi * 8), bb, acc2[j2]);
    }
    #pragma unroll
    for (int j2 = 0; j2 < 2; ++j2) {
      int jm = g * 2 + j2;
      #pragma unroll
      for (int rq = 0; rq < 4; ++rq) {
        int j0 = jm * 32 + rq * 8 + hi * 4;
        float4 hv = h4[(size_t)nc * 32 + (j0 >> 2)];
        float4 o;
        o.x = hv.x + acc2[j2][rq * 4 + 0] + sb2[j0 + 0];
        o.y = hv.y + acc2[j2][rq * 4 + 1] + sb2[j0 + 1];
        o.z = hv.z + acc2[j2][rq * 4 + 2] + sb2[j0 + 2];
        o.w = hv.w + acc2[j2][rq * 4 + 3] + sb2[j0 + 3];
        if (va) ((float4*)outH)[(size_t)nc * 32 + (j0 >> 2)] = o;
      }
    }
  }
}

// ===================== LAUNCH =====================

extern "C" void kernel_launch(void* const* d_in, const int* in_sizes, int n_in,
                              void* d_out, int out_size, void* d_ws, size_t ws_size,
                              hipStream_t stream) {
  const float* h    = (const float*)d_in[0];
  const float* x    = (const float*)d_in[1];
  const int*   src  = (const int*)d_in[2];
  const int*   dst  = (const int*)d_in[3];
  const float* dist = (const float*)d_in[4];
  const float* bpp  = (const float*)d_in[5];
  const float* msa  = (const float*)d_in[6];
  const float* chem = (const float*)d_in[7];
  const float* rel  = (const float*)d_in[8];
  const float* cbm  = (const float*)d_in[9];
  const float* mW1  = (const float*)d_in[10];
  const float* mb1  = (const float*)d_in[11];
  const float* mW2  = (const float*)d_in[12];
  const float* mb2  = (const float*)d_in[13];
  const float* hW1  = (const float*)d_in[14];
  const float* hb1  = (const float*)d_in[15];
  const float* hW2  = (const float*)d_in[16];
  const float* hb2  = (const float*)d_in[17];
  const float* cW1  = (const float*)d_in[18];
  const float* cb1  = (const float*)d_in[19];
  const float* cW2  = (const float*)d_in[20];
  const float* cb2  = (const float*)d_in[21];

  int N = in_sizes[0] / 128;
  int E = in_sizes[2];

  size_t off = 0;
  auto A = [&](size_t b) { size_t o = off; off += (b + 255) & ~(size_t)255; return o; };
  size_t o_cnt  = A((size_t)N * 4);
  size_t o_rs   = A((size_t)N * 4);
  size_t o_head = A((size_t)N * 4);
  size_t o_rec  = A((size_t)E * 32);
  size_t o_coef = A((size_t)E * 4);
  size_t o_bs   = A(1024);
  size_t o_hbf  = A((size_t)N * 256);
  size_t o_mibf = A((size_t)N * 256);
  size_t o_big  = A((size_t)E * 256);   // t1 -> m_ij (in-place) -> t1h

  char* W = (char*)d_ws;
  int*   cnt32 = (int*)(W + o_cnt);
  int*   rs    = (int*)(W + o_rs);
  int*   head  = (int*)(W + o_head);
  int*   rec   = (int*)(W + o_rec);
  float* coef  = (float*)(W + o_coef);
  int*   bsums = (int*)(W + o_bs);
  char*  hbf   = W + o_hbf;
  char*  mibf  = W + o_mibf;
  char*  big   = W + o_big;

  hipMemsetAsync(cnt32, 0, (size_t)N * 4, stream);
  kconv<<<(N * 16 + 255) / 256, 256, 0, stream>>>(h, hbf, N * 16);
  khist<<<(E + 255) / 256, 256, 0, stream>>>(src, cnt32, E);
  int nb = (N + 1023) / 1024;
  kscan1<<<nb, 1024, 0, stream>>>(cnt32, rs, bsums, N);
  kscan2<<<1, 64, 0, stream>>>(bsums, nb);
  kscan3<<<nb, 1024, 0, stream>>>(bsums, rs, head, N);
  kscatter<<<(E + 255) / 256, 256, 0, stream>>>(src, dst, dist, bpp, msa, chem, rel, cbm,
                                                head, rec, E);
  kedgeA<<<512, 512, 0, stream>>>(hbf, rec, mW1, mb1, big, E);
  kedgeB<<<512, 512, 0, stream>>>(big, mW2, mb2, cW1, cb1, cW2, cb2, coef, E);
  kagg<<<(N + 15) / 16, 256, 0, stream>>>(big, rs, cnt32, mibf, N);
  kaggx<<<(N + 255) / 256, 256, 0, stream>>>(rs, cnt32, coef, rec, x,
                                             (float*)d_out + (size_t)N * 128, N);
  int tb = ((N + 31) / 32 + 7) / 8;
  knode1<<<tb, 512, 0, stream>>>(hbf, mibf, hW1, hb1, big, N);
  knode2<<<tb, 512, 0, stream>>>(big, hW2, hb2, h, (float*)d_out, N);
}